// Round 1
// baseline (120.352 us; speedup 1.0000x reference)
//
#include <hip/hip_runtime.h>

// Problem: B=4, N=1024, H=64.
// d_out layout: [0 .. 262143] updated (b,i,d) ; [262144 .. 4456447] attn (b,i,j)
// d_ws layout (floats): hiT [4][64][1024] @0 ; hjT @262144 ; partials[4][4][1024][64] @524288
#define ATTN_OFF 262144

typedef float4 f4;
__device__ __forceinline__ f4 ld4(const float* p) { return *reinterpret_cast<const f4*>(p); }
__device__ __forceinline__ void st4(float* p, f4 v) { *reinterpret_cast<f4*>(p) = v; }

// ---------------- Kernel A: hi' = x@W1a^T + b1 ; hj = x@W1b^T, stored transposed [b][h][i]
// grid (16 i-chunks, 4 b, 2 z), block 256. z=0 -> hi (cols 0..63 of W1 rows, +b1), z=1 -> hj.
__global__ __launch_bounds__(256, 4)
void ka_proj(const float* __restrict__ x, const float* __restrict__ W1,
             const float* __restrict__ b1,
             float* __restrict__ hiT, float* __restrict__ hjT) {
    __shared__ float xT[64 * 68];   // xT[d][i], pad 68 -> 2-way-max conflicts on scatter
    __shared__ float w1T[64 * 68];  // w1T[d][c] = W1[c][z*64+d]
    const int t  = threadIdx.x;
    const int i0 = blockIdx.x * 64;
    const int b  = blockIdx.y;
    const int z  = blockIdx.z;
    const int lo = t & 15;   // 0..15
    const int dq = t >> 4;   // 0..15
#pragma unroll
    for (int p = 0; p < 4; ++p) {
        const int il = p * 16 + lo;  // i (and c) index 0..63
        f4 v = ld4(&x[(size_t)(b * 1024 + i0 + il) * 64 + dq * 4]);
        xT[(dq * 4 + 0) * 68 + il] = v.x;
        xT[(dq * 4 + 1) * 68 + il] = v.y;
        xT[(dq * 4 + 2) * 68 + il] = v.z;
        xT[(dq * 4 + 3) * 68 + il] = v.w;
        f4 w = ld4(&W1[(size_t)il * 128 + z * 64 + dq * 4]);
        w1T[(dq * 4 + 0) * 68 + il] = w.x;
        w1T[(dq * 4 + 1) * 68 + il] = w.y;
        w1T[(dq * 4 + 2) * 68 + il] = w.z;
        w1T[(dq * 4 + 3) * 68 + il] = w.w;
    }
    __syncthreads();
    const int tx = t & 15;  // c4 = tx*4
    const int ty = t >> 4;  // i4 = ty*4
    float acc[4][4];
    if (z == 0) {
        f4 bv = ld4(&b1[tx * 4]);
        float ba[4] = {bv.x, bv.y, bv.z, bv.w};
#pragma unroll
        for (int ii = 0; ii < 4; ++ii)
#pragma unroll
            for (int cc = 0; cc < 4; ++cc) acc[ii][cc] = ba[cc];
    } else {
#pragma unroll
        for (int ii = 0; ii < 4; ++ii)
#pragma unroll
            for (int cc = 0; cc < 4; ++cc) acc[ii][cc] = 0.f;
    }
#pragma unroll 8
    for (int d = 0; d < 64; ++d) {
        f4 xv = ld4(&xT[d * 68 + ty * 4]);    // 4 addrs (ty) -> broadcast
        f4 wv = ld4(&w1T[d * 68 + tx * 4]);   // 16 addrs -> ~2-way
        float xa[4] = {xv.x, xv.y, xv.z, xv.w};
        float wa[4] = {wv.x, wv.y, wv.z, wv.w};
#pragma unroll
        for (int ii = 0; ii < 4; ++ii)
#pragma unroll
            for (int cc = 0; cc < 4; ++cc)
                acc[ii][cc] = fmaf(xa[ii], wa[cc], acc[ii][cc]);
    }
    float* outp = z ? hjT : hiT;
#pragma unroll
    for (int cc = 0; cc < 4; ++cc) {
        f4 o = make_float4(acc[0][cc], acc[1][cc], acc[2][cc], acc[3][cc]);
        st4(&outp[(size_t)(b * 64 + tx * 4 + cc) * 1024 + i0 + ty * 4], o);
    }
}

// ---------------- Kernel B: logits[b,i,j] = sum_h relu(hi'[i,h]+hj[j,h]) * w2[h]
// grid (16 jT, 16 iT, 4 b), block 256. Writes into d_out attn region (raw logits).
__global__ __launch_bounds__(256, 4)
void kb_logits(const float* __restrict__ hiT, const float* __restrict__ hjT,
               const float* __restrict__ W2, float* __restrict__ out) {
    __shared__ float s_hi[64 * 64];  // [h][i] unpadded: reads broadcast, staging is flat copy
    __shared__ float s_hj[64 * 64];
    __shared__ float s_w2[64];
    const int t  = threadIdx.x;
    const int jT = blockIdx.x * 64;
    const int iT = blockIdx.y * 64;
    const int b  = blockIdx.z;
    const int f  = (t & 15) * 4;   // column 0..63
    const int hh = t >> 4;         // 0..15
#pragma unroll
    for (int hp = 0; hp < 4; ++hp) {
        const int h = hp * 16 + hh;
        st4(&s_hi[h * 64 + f], ld4(&hiT[(size_t)(b * 64 + h) * 1024 + iT + f]));
        st4(&s_hj[h * 64 + f], ld4(&hjT[(size_t)(b * 64 + h) * 1024 + jT + f]));
    }
    if (t < 16) st4(&s_w2[t * 4], ld4(&W2[t * 4]));
    __syncthreads();
    const int tx = t & 15;  // j4
    const int ty = t >> 4;  // i4
    float acc[4][4];
#pragma unroll
    for (int ii = 0; ii < 4; ++ii)
#pragma unroll
        for (int jj = 0; jj < 4; ++jj) acc[ii][jj] = 0.f;
#pragma unroll 8
    for (int h = 0; h < 64; ++h) {
        f4 av = ld4(&s_hi[h * 64 + ty * 4]);  // broadcast (4 addrs)
        f4 bv = ld4(&s_hj[h * 64 + tx * 4]);  // ~2-way
        const float w = s_w2[h];              // uniform -> broadcast
        float aa[4] = {av.x, av.y, av.z, av.w};
        float bb[4] = {bv.x, bv.y, bv.z, bv.w};
#pragma unroll
        for (int ii = 0; ii < 4; ++ii)
#pragma unroll
            for (int jj = 0; jj < 4; ++jj)
                acc[ii][jj] = fmaf(fmaxf(aa[ii] + bb[jj], 0.f), w, acc[ii][jj]);
    }
    float* logits = out + ATTN_OFF;
#pragma unroll
    for (int ii = 0; ii < 4; ++ii) {
        f4 o = make_float4(acc[ii][0], acc[ii][1], acc[ii][2], acc[ii][3]);
        st4(&logits[(size_t)(b * 1024 + iT + ty * 4 + ii) * 1024 + jT + tx * 4], o);
    }
}

// ---------------- Kernel C: in-place softmax over each row of 1024 logits.
// grid 1024 blocks x 256 (4 waves -> 4 rows/block). Row lives in 4 float4 regs/lane.
__global__ __launch_bounds__(256, 4)
void kc_softmax(float* __restrict__ out) {
    float* logits = out + ATTN_OFF;
    const int t    = threadIdx.x;
    const int lane = t & 63;
    const int row  = blockIdx.x * 4 + (t >> 6);
    float* p = logits + (size_t)row * 1024;
    f4 v[4];
    float m = -3.0e38f;
#pragma unroll
    for (int k = 0; k < 4; ++k) {
        v[k] = ld4(&p[lane * 4 + k * 256]);
        m = fmaxf(m, fmaxf(fmaxf(v[k].x, v[k].y), fmaxf(v[k].z, v[k].w)));
    }
#pragma unroll
    for (int off = 32; off > 0; off >>= 1) m = fmaxf(m, __shfl_xor(m, off));
    float s = 0.f;
#pragma unroll
    for (int k = 0; k < 4; ++k) {
        v[k].x = __expf(v[k].x - m);
        v[k].y = __expf(v[k].y - m);
        v[k].z = __expf(v[k].z - m);
        v[k].w = __expf(v[k].w - m);
        s += v[k].x + v[k].y + v[k].z + v[k].w;
    }
#pragma unroll
    for (int off = 32; off > 0; off >>= 1) s += __shfl_xor(s, off);
    const float inv = 1.0f / s;
#pragma unroll
    for (int k = 0; k < 4; ++k) {
        v[k].x *= inv; v[k].y *= inv; v[k].z *= inv; v[k].w *= inv;
        st4(&p[lane * 4 + k * 256], v[k]);
    }
}

// ---------------- Kernel D: partial updated = attn @ x, K-split over j.
// grid (4 ksplit, 16 iT, 4 b), block 256. Two 128-j chunks per block. LDS = 64 KB exactly.
__global__ __launch_bounds__(256)
void kd_partial(const float* __restrict__ outbuf, const float* __restrict__ x,
                float* __restrict__ part) {
    __shared__ float pT[128 * 64];  // [j][i] transposed attn tile
    __shared__ float xs[128 * 64];  // [j][d] natural
    const float* attn = outbuf + ATTN_OFF;
    const int t  = threadIdx.x;
    const int ks = blockIdx.x;       // 0..3
    const int iT = blockIdx.y * 64;
    const int b  = blockIdx.z;
    const int tx = t & 15;  // d4
    const int ty = t >> 4;  // i4
    float acc[4][4];
#pragma unroll
    for (int ii = 0; ii < 4; ++ii)
#pragma unroll
        for (int dd = 0; dd < 4; ++dd) acc[ii][dd] = 0.f;
    for (int jc = 0; jc < 2; ++jc) {
        const int j0 = ks * 256 + jc * 128;
        __syncthreads();
        // stage pT (transpose): 8 passes, 4-way max write conflicts
#pragma unroll
        for (int ps = 0; ps < 8; ++ps) {
            const int pi = ps & 3, pj = ps >> 2;
            const int il = pi * 16 + (t & 15);
            const int jr = pj * 64 + (t >> 4) * 4;
            f4 v = ld4(&attn[(size_t)(b * 1024 + iT + il) * 1024 + j0 + jr]);
            pT[(jr + 0) * 64 + il] = v.x;
            pT[(jr + 1) * 64 + il] = v.y;
            pT[(jr + 2) * 64 + il] = v.z;
            pT[(jr + 3) * 64 + il] = v.w;
        }
        // stage xs (flat copy, conflict-free)
#pragma unroll
        for (int ps = 0; ps < 8; ++ps) {
            const int idx = ps * 256 + t;          // float4 index
            const int j   = idx >> 4;
            const int dsl = (idx & 15) * 4;
            st4(&xs[idx * 4], ld4(&x[(size_t)(b * 1024 + j0 + j) * 64 + dsl]));
        }
        __syncthreads();
#pragma unroll 8
        for (int j = 0; j < 128; ++j) {
            f4 pv = ld4(&pT[j * 64 + ty * 4]);  // broadcast
            f4 xv = ld4(&xs[j * 64 + tx * 4]);  // ~2-way
            float pa[4] = {pv.x, pv.y, pv.z, pv.w};
            float xa[4] = {xv.x, xv.y, xv.z, xv.w};
#pragma unroll
            for (int ii = 0; ii < 4; ++ii)
#pragma unroll
                for (int dd = 0; dd < 4; ++dd)
                    acc[ii][dd] = fmaf(pa[ii], xa[dd], acc[ii][dd]);
        }
    }
#pragma unroll
    for (int ii = 0; ii < 4; ++ii) {
        f4 o = make_float4(acc[ii][0], acc[ii][1], acc[ii][2], acc[ii][3]);
        st4(&part[(size_t)((ks * 4 + b) * 1024 + iT + ty * 4 + ii) * 64 + tx * 4], o);
    }
}

// ---------------- Kernel E: updated = sum of 4 partials -> d_out[0:262144]
__global__ __launch_bounds__(256, 4)
void ke_reduce(const float* __restrict__ part, float* __restrict__ out) {
    const int g = blockIdx.x * 256 + threadIdx.x;  // float4 index, 65536 total
    f4 a0 = ld4(&part[(size_t)0 * 262144 + g * 4]);
    f4 a1 = ld4(&part[(size_t)1 * 262144 + g * 4]);
    f4 a2 = ld4(&part[(size_t)2 * 262144 + g * 4]);
    f4 a3 = ld4(&part[(size_t)3 * 262144 + g * 4]);
    f4 o = make_float4(a0.x + a1.x + a2.x + a3.x,
                       a0.y + a1.y + a2.y + a3.y,
                       a0.z + a1.z + a2.z + a3.z,
                       a0.w + a1.w + a2.w + a3.w);
    st4(&out[(size_t)g * 4], o);
}

extern "C" void kernel_launch(void* const* d_in, const int* in_sizes, int n_in,
                              void* d_out, int out_size, void* d_ws, size_t ws_size,
                              hipStream_t stream) {
    const float* x  = (const float*)d_in[0];
    const float* W1 = (const float*)d_in[1];
    const float* b1 = (const float*)d_in[2];
    const float* W2 = (const float*)d_in[3];
    // d_in[4] = b2: softmax is shift-invariant and logits are never output -> unused.
    float* out = (float*)d_out;
    float* ws  = (float*)d_ws;
    float* hiT  = ws;            // 262144 floats
    float* hjT  = ws + 262144;   // 262144 floats
    float* part = ws + 524288;   // 1048576 floats

    ka_proj   <<<dim3(16, 4, 2),  256, 0, stream>>>(x, W1, b1, hiT, hjT);
    kb_logits <<<dim3(16, 16, 4), 256, 0, stream>>>(hiT, hjT, W2, out);
    kc_softmax<<<dim3(1024),      256, 0, stream>>>(out);
    kd_partial<<<dim3(4, 16, 4),  256, 0, stream>>>(out, x, part);
    ke_reduce <<<dim3(256),       256, 0, stream>>>(part, out);
}

// Round 2
// 118.251 us; speedup vs baseline: 1.0178x; 1.0178x over previous
//
#include <hip/hip_runtime.h>

// Problem: B=4, N=1024, H=64.
// d_out layout: [0 .. 262143] updated (b,i,d) ; [262144 .. 4456447] attn (b,i,j)
#define ATTN_OFF 262144

// ws layout (floats):
#define WS_HIT   0          // hiT [4][64][1024]            262144
#define WS_HJT   262144     // hjT [4][64][1024]            262144
#define WS_LOG   524288     // logits [4][1024][1024]       4194304
#define WS_SMAX  4718592    // smax [16][4096]              65536
#define WS_SSUM  4784128    // ssum [16][4096]              65536
#define WS_ROWM  4849664    // rowM [4096]                  4096
#define WS_ROWI  4853760    // rowInv [4096]                4096
#define WS_PART  4857856    // part [16][4096][64]          4194304
// total 9052160 floats = 36.2 MB

typedef float4 f4;
__device__ __forceinline__ f4 ld4(const float* p) { return *reinterpret_cast<const f4*>(p); }
__device__ __forceinline__ void st4(float* p, f4 v) { *reinterpret_cast<f4*>(p) = v; }

// ---------------- Kernel A: hi' = x@W1a^T + b1 ; hj = x@W1b^T, stored transposed [b][h][i]
__global__ __launch_bounds__(256, 4)
void ka_proj(const float* __restrict__ x, const float* __restrict__ W1,
             const float* __restrict__ b1,
             float* __restrict__ hiT, float* __restrict__ hjT) {
    __shared__ float xT[64 * 68];
    __shared__ float w1T[64 * 68];
    const int t  = threadIdx.x;
    const int i0 = blockIdx.x * 64;
    const int b  = blockIdx.y;
    const int z  = blockIdx.z;
    const int lo = t & 15;
    const int dq = t >> 4;
#pragma unroll
    for (int p = 0; p < 4; ++p) {
        const int il = p * 16 + lo;
        f4 v = ld4(&x[(size_t)(b * 1024 + i0 + il) * 64 + dq * 4]);
        xT[(dq * 4 + 0) * 68 + il] = v.x;
        xT[(dq * 4 + 1) * 68 + il] = v.y;
        xT[(dq * 4 + 2) * 68 + il] = v.z;
        xT[(dq * 4 + 3) * 68 + il] = v.w;
        f4 w = ld4(&W1[(size_t)il * 128 + z * 64 + dq * 4]);
        w1T[(dq * 4 + 0) * 68 + il] = w.x;
        w1T[(dq * 4 + 1) * 68 + il] = w.y;
        w1T[(dq * 4 + 2) * 68 + il] = w.z;
        w1T[(dq * 4 + 3) * 68 + il] = w.w;
    }
    __syncthreads();
    const int tx = t & 15;
    const int ty = t >> 4;
    float acc[4][4];
    if (z == 0) {
        f4 bv = ld4(&b1[tx * 4]);
        float ba[4] = {bv.x, bv.y, bv.z, bv.w};
#pragma unroll
        for (int ii = 0; ii < 4; ++ii)
#pragma unroll
            for (int cc = 0; cc < 4; ++cc) acc[ii][cc] = ba[cc];
    } else {
#pragma unroll
        for (int ii = 0; ii < 4; ++ii)
#pragma unroll
            for (int cc = 0; cc < 4; ++cc) acc[ii][cc] = 0.f;
    }
#pragma unroll 8
    for (int d = 0; d < 64; ++d) {
        f4 xv = ld4(&xT[d * 68 + ty * 4]);
        f4 wv = ld4(&w1T[d * 68 + tx * 4]);
        float xa[4] = {xv.x, xv.y, xv.z, xv.w};
        float wa[4] = {wv.x, wv.y, wv.z, wv.w};
#pragma unroll
        for (int ii = 0; ii < 4; ++ii)
#pragma unroll
            for (int cc = 0; cc < 4; ++cc)
                acc[ii][cc] = fmaf(xa[ii], wa[cc], acc[ii][cc]);
    }
    float* outp = z ? hjT : hiT;
#pragma unroll
    for (int cc = 0; cc < 4; ++cc) {
        f4 o = make_float4(acc[0][cc], acc[1][cc], acc[2][cc], acc[3][cc]);
        st4(&outp[(size_t)(b * 64 + tx * 4 + cc) * 1024 + i0 + ty * 4], o);
    }
}

// ---------------- Kernel B: logits + fused per-chunk softmax stats.
// grid (16 jT, 8 iT, 4 b) = 512 blocks (2/CU), block 256. Tile 128i x 64j, 8x4/thread.
__global__ __launch_bounds__(256, 2)
void kb_logits(const float* __restrict__ hiT, const float* __restrict__ hjT,
               const float* __restrict__ W2, float* __restrict__ logits,
               float* __restrict__ smax, float* __restrict__ ssum) {
    __shared__ float s_hi[64 * 128];  // [h][i]
    __shared__ float s_hj[64 * 64];   // [h][j]
    __shared__ float s_w2[64];
    const int t  = threadIdx.x;
    const int jT = blockIdx.x;   // 0..15 (64 j each)
    const int iT = blockIdx.y;   // 0..7  (128 i each)
    const int b  = blockIdx.z;
#pragma unroll
    for (int p = 0; p < 8; ++p) {  // s_hi: 2048 f4
        const int idx = p * 256 + t;
        const int h   = idx >> 5;
        const int c4  = (idx & 31) * 4;
        st4(&s_hi[h * 128 + c4], ld4(&hiT[(size_t)(b * 64 + h) * 1024 + iT * 128 + c4]));
    }
#pragma unroll
    for (int p = 0; p < 4; ++p) {  // s_hj: 1024 f4
        const int idx = p * 256 + t;
        const int h   = idx >> 4;
        const int c4  = (idx & 15) * 4;
        st4(&s_hj[h * 64 + c4], ld4(&hjT[(size_t)(b * 64 + h) * 1024 + jT * 64 + c4]));
    }
    if (t < 16) st4(&s_w2[t * 4], ld4(&W2[t * 4]));
    __syncthreads();
    const int tx = t & 15;  // j4
    const int ty = t >> 4;  // i8
    float acc[8][4];
#pragma unroll
    for (int ii = 0; ii < 8; ++ii)
#pragma unroll
        for (int jj = 0; jj < 4; ++jj) acc[ii][jj] = 0.f;
#pragma unroll 2
    for (int h = 0; h < 64; ++h) {
        f4 a0 = ld4(&s_hi[h * 128 + ty * 8]);      // 4 addrs/wave -> bcast
        f4 a1 = ld4(&s_hi[h * 128 + ty * 8 + 4]);
        f4 bv = ld4(&s_hj[h * 64 + tx * 4]);       // 2-way, free
        const float w = s_w2[h];
        float aa[8] = {a0.x, a0.y, a0.z, a0.w, a1.x, a1.y, a1.z, a1.w};
        float bb[4] = {bv.x, bv.y, bv.z, bv.w};
#pragma unroll
        for (int ii = 0; ii < 8; ++ii)
#pragma unroll
            for (int jj = 0; jj < 4; ++jj)
                acc[ii][jj] = fmaf(fmaxf(aa[ii] + bb[jj], 0.f), w, acc[ii][jj]);
    }
    // write logits (f4 per row) + per-row chunk stats via 16-lane shuffles
#pragma unroll
    for (int ii = 0; ii < 8; ++ii) {
        const int row = b * 1024 + iT * 128 + ty * 8 + ii;
        f4 o = make_float4(acc[ii][0], acc[ii][1], acc[ii][2], acc[ii][3]);
        st4(&logits[(size_t)row * 1024 + jT * 64 + tx * 4], o);
        float m = fmaxf(fmaxf(acc[ii][0], acc[ii][1]), fmaxf(acc[ii][2], acc[ii][3]));
#pragma unroll
        for (int d = 1; d < 16; d <<= 1) m = fmaxf(m, __shfl_xor(m, d));
        float s = __expf(acc[ii][0] - m) + __expf(acc[ii][1] - m) +
                  __expf(acc[ii][2] - m) + __expf(acc[ii][3] - m);
#pragma unroll
        for (int d = 1; d < 16; d <<= 1) s += __shfl_xor(s, d);
        if (tx == 0) {
            smax[jT * 4096 + row] = m;
            ssum[jT * 4096 + row] = s;
        }
    }
}

// ---------------- Kernel R: merge 16 chunk-stats per row -> (M, 1/L)
__global__ __launch_bounds__(256)
void kredux(const float* __restrict__ smax, const float* __restrict__ ssum,
            float* __restrict__ rowM, float* __restrict__ rowInv) {
    const int r = blockIdx.x * 256 + threadIdx.x;  // 4096 rows
    float mv[16], sv[16];
#pragma unroll
    for (int c = 0; c < 16; ++c) { mv[c] = smax[c * 4096 + r]; sv[c] = ssum[c * 4096 + r]; }
    float M = mv[0];
#pragma unroll
    for (int c = 1; c < 16; ++c) M = fmaxf(M, mv[c]);
    float L = 0.f;
#pragma unroll
    for (int c = 0; c < 16; ++c) L += sv[c] * __expf(mv[c] - M);
    rowM[r]   = M;
    rowInv[r] = 1.0f / L;
}

// ---------------- Kernel D: normalize logits -> attn (d_out) + AV partials.
// grid (16 ks, 4 iT, 4 b) = 256 blocks, block 256. Tile: 256 i x 64 j, 8i x 8d/thread.
__global__ __launch_bounds__(256)
void kd_av(const float* __restrict__ logits, const float* __restrict__ rowM,
           const float* __restrict__ rowInv, const float* __restrict__ x,
           float* __restrict__ attn, float* __restrict__ part) {
    __shared__ float s_p[64 * 260];  // [j][i] padded (260: b128-aligned, reads 2-way)
    __shared__ float s_x[64 * 64];   // [j][d]
    __shared__ float s_m[256];
    __shared__ float s_il[256];
    const int t  = threadIdx.x;
    const int ks = blockIdx.x;        // j-chunk 0..15
    const int iT = blockIdx.y;        // 0..3
    const int b  = blockIdx.z;
    const int i0 = iT * 256;
    const int j0 = ks * 64;
    const int gr = b * 1024 + i0;     // global row base
    s_m[t]  = rowM[gr + t];
    s_il[t] = rowInv[gr + t];
#pragma unroll
    for (int p = 0; p < 4; ++p) {     // s_x: 1024 f4
        const int idx = p * 256 + t;
        const int j   = idx >> 4;
        const int d4  = (idx & 15) * 4;
        st4(&s_x[j * 64 + d4], ld4(&x[(size_t)(b * 1024 + j0 + j) * 64 + d4]));
    }
    __syncthreads();
    // stage + normalize + write attn (coalesced) + transpose-scatter to LDS
#pragma unroll 4
    for (int it = 0; it < 16; ++it) {
        const int idx = it * 256 + t;
        const int rl  = idx >> 4;          // 0..255
        const int j4  = (idx & 15) * 4;
        f4 v = ld4(&logits[(size_t)(gr + rl) * 1024 + j0 + j4]);
        const float m  = s_m[rl];
        const float il = s_il[rl];
        f4 pv;
        pv.x = __expf(v.x - m) * il;
        pv.y = __expf(v.y - m) * il;
        pv.z = __expf(v.z - m) * il;
        pv.w = __expf(v.w - m) * il;
        st4(&attn[(size_t)(gr + rl) * 1024 + j0 + j4], pv);
        s_p[(j4 + 0) * 260 + rl] = pv.x;
        s_p[(j4 + 1) * 260 + rl] = pv.y;
        s_p[(j4 + 2) * 260 + rl] = pv.z;
        s_p[(j4 + 3) * 260 + rl] = pv.w;
    }
    __syncthreads();
    const int tx = t & 7;   // d8
    const int ty = t >> 3;  // i8 (0..31)
    float acc[8][8];
#pragma unroll
    for (int ii = 0; ii < 8; ++ii)
#pragma unroll
        for (int dd = 0; dd < 8; ++dd) acc[ii][dd] = 0.f;
#pragma unroll 2
    for (int j = 0; j < 64; ++j) {
        f4 a0 = ld4(&s_p[j * 260 + ty * 8]);
        f4 a1 = ld4(&s_p[j * 260 + ty * 8 + 4]);
        f4 b0 = ld4(&s_x[j * 64 + tx * 8]);
        f4 b1 = ld4(&s_x[j * 64 + tx * 8 + 4]);
        float aa[8] = {a0.x, a0.y, a0.z, a0.w, a1.x, a1.y, a1.z, a1.w};
        float bb[8] = {b0.x, b0.y, b0.z, b0.w, b1.x, b1.y, b1.z, b1.w};
#pragma unroll
        for (int ii = 0; ii < 8; ++ii)
#pragma unroll
            for (int dd = 0; dd < 8; ++dd)
                acc[ii][dd] = fmaf(aa[ii], bb[dd], acc[ii][dd]);
    }
#pragma unroll
    for (int ii = 0; ii < 8; ++ii) {
        const size_t o = (size_t)(ks * 4096 + gr + ty * 8 + ii) * 64 + tx * 8;
        st4(&part[o],     make_float4(acc[ii][0], acc[ii][1], acc[ii][2], acc[ii][3]));
        st4(&part[o + 4], make_float4(acc[ii][4], acc[ii][5], acc[ii][6], acc[ii][7]));
    }
}

// ---------------- Kernel E: updated = sum of 16 partials -> d_out[0:262144]
__global__ __launch_bounds__(256)
void ke_reduce(const float* __restrict__ part, float* __restrict__ out) {
    const int g = blockIdx.x * 256 + threadIdx.x;  // f4 index, 65536 total
    f4 a = ld4(&part[(size_t)g * 4]);
#pragma unroll
    for (int ks = 1; ks < 16; ++ks) {
        f4 v = ld4(&part[(size_t)ks * 262144 + g * 4]);
        a.x += v.x; a.y += v.y; a.z += v.z; a.w += v.w;
    }
    st4(&out[(size_t)g * 4], a);
}

extern "C" void kernel_launch(void* const* d_in, const int* in_sizes, int n_in,
                              void* d_out, int out_size, void* d_ws, size_t ws_size,
                              hipStream_t stream) {
    const float* x  = (const float*)d_in[0];
    const float* W1 = (const float*)d_in[1];
    const float* b1 = (const float*)d_in[2];
    const float* W2 = (const float*)d_in[3];
    // d_in[4] = b2: softmax shift-invariance -> unused.
    float* out = (float*)d_out;
    float* ws  = (float*)d_ws;
    float* hiT    = ws + WS_HIT;
    float* hjT    = ws + WS_HJT;
    float* logits = ws + WS_LOG;
    float* smax   = ws + WS_SMAX;
    float* ssum   = ws + WS_SSUM;
    float* rowM   = ws + WS_ROWM;
    float* rowInv = ws + WS_ROWI;
    float* part   = ws + WS_PART;

    ka_proj  <<<dim3(16, 4, 2),  256, 0, stream>>>(x, W1, b1, hiT, hjT);
    kb_logits<<<dim3(16, 8, 4),  256, 0, stream>>>(hiT, hjT, W2, logits, smax, ssum);
    kredux   <<<dim3(16),        256, 0, stream>>>(smax, ssum, rowM, rowInv);
    kd_av    <<<dim3(16, 4, 4),  256, 0, stream>>>(logits, rowM, rowInv, x,
                                                   out + ATTN_OFF, part);
    ke_reduce<<<dim3(256),       256, 0, stream>>>(part, out);
}